// Round 15
// baseline (148.251 us; speedup 1.0000x reference)
//
#include <hip/hip_runtime.h>
#include <hip/hip_bf16.h>

#define TT 64
#define DD 255
#define KK 256
#define MM 512
#define CC 8
#define BB 4096
#define RB 16    // rows per block = MFMA M
#define TPB 16   // trees per block (4 per wave)
#define XS 16    // xsi feature stride in halfs (32B)

typedef _Float16 h8 __attribute__((ext_vector_type(8)));
typedef _Float16 h2v __attribute__((ext_vector_type(2)));
typedef float f4 __attribute__((ext_vector_type(4)));

// cvt_pkrtz returns __fp16x2; bit-cast to our _Float16x2
__device__ __forceinline__ h2v pkrtz(float a, float b) {
    return __builtin_bit_cast(h2v, __builtin_amdgcn_cvt_pkrtz(a, b));
}

__device__ __forceinline__ float wave_sum(float v) {
    v += __shfl_down(v, 32, 64);
    v += __shfl_down(v, 16, 64);
    v += __shfl_down(v, 8, 64);
    v += __shfl_down(v, 4, 64);
    v += __shfl_down(v, 2, 64);
    v += __shfl_down(v, 1, 64);
    return v;
}

// ---------------- kernel 0: extract feature index from one-hot W1 ----------
__global__ void feat_kernel(const float* __restrict__ W1, int* __restrict__ feat) {
    const int row = blockIdx.x * 4 + (threadIdx.x >> 6);
    const int lane = threadIdx.x & 63;
    const float4* r = reinterpret_cast<const float4*>(W1 + (size_t)row * MM);
    float4 a = r[lane];
    float4 b = r[lane + 64];
    float ba = (float)(4 * lane);
    float bb = (float)(4 * (lane + 64));
    float acc = 0.0f;
    acc = fmaf(a.x, ba,        acc);
    acc = fmaf(a.y, ba + 1.0f, acc);
    acc = fmaf(a.z, ba + 2.0f, acc);
    acc = fmaf(a.w, ba + 3.0f, acc);
    acc = fmaf(b.x, bb,        acc);
    acc = fmaf(b.y, bb + 1.0f, acc);
    acc = fmaf(b.z, bb + 2.0f, acc);
    acc = fmaf(b.w, bb + 3.0f, acc);
    acc = wave_sum(acc);
    if (lane == 0) feat[row] = (int)(acc + 0.5f);
}

// ---------------- kernel 0b: Cw -> f16 B-frag order in global ws ----------
// cwT[(((t*8+c)*8+cls)*4+slot)*8+j] = Cw[t][c*32+slot*8+j][cls]  (256 KB)
__global__ void cwt_kernel(const float* __restrict__ Cw, _Float16* __restrict__ cwT) {
    int idx = blockIdx.x * 256 + threadIdx.x;   // t*256 + k
    int t = idx >> 8, k = idx & 255;
    int c = k >> 5, sl = (k >> 3) & 3, j = k & 7;
    const float4* p = reinterpret_cast<const float4*>(Cw + (size_t)idx * CC);
    float4 p0 = p[0], p1 = p[1];
    _Float16* base = cwT + ((((t * 8 + c) * 8) * 4 + sl) * 8 + j);  // cls stride 32
    base[0 * 32] = (_Float16)p0.x;
    base[1 * 32] = (_Float16)p0.y;
    base[2 * 32] = (_Float16)p0.z;
    base[3 * 32] = (_Float16)p0.w;
    base[4 * 32] = (_Float16)p1.x;
    base[5 * 32] = (_Float16)p1.y;
    base[6 * 32] = (_Float16)p1.z;
    base[7 * 32] = (_Float16)p1.w;
}

// ---------------- kernel 0c: per-(t,chunk,slot) node metadata -------------
// m46  : nodes {n4, n5, q0, q0+1}  (depths 4,5,6 on this slot's path)
// m7   : depth-7 quad r0..r0+3, r0 = 127+16c+4*slot
// mPre : nodes 0..14 per tree (wave-uniform prefix + depth-3 block)
// c1 premultiplied by -10*log2(e).
__global__ void meta_kernel(const int* __restrict__ feat, const float* __restrict__ b1,
                            int4* __restrict__ m46f, float4* __restrict__ m46c,
                            int4* __restrict__ m7f, float4* __restrict__ m7c,
                            int* __restrict__ mPf, float* __restrict__ mPc) {
    int idx = blockIdx.x * 256 + threadIdx.x;   // t*32 + c*4 + slot  (2048 total)
    if (idx >= TT * 32) return;
    int t = idx >> 5, rem = idx & 31;
    int c = rem >> 2, sl = rem & 3;
    int b3 = sl >> 1, b4 = sl & 1;
    int base = t * DD;
    const float K1 = -14.426950408889634f;
    int n4 = base + 15 + 2 * c + b3;
    int n5 = base + 31 + 4 * c + 2 * b3 + b4;
    int q0 = base + 63 + 8 * c + 4 * b3 + 2 * b4;
    m46f[idx] = make_int4(feat[n4], feat[n5], feat[q0], feat[q0 + 1]);
    m46c[idx] = make_float4(K1 * b1[n4], K1 * b1[n5], K1 * b1[q0], K1 * b1[q0 + 1]);
    int r0 = base + 127 + 16 * c + 4 * sl;
    m7f[idx] = make_int4(feat[r0], feat[r0 + 1], feat[r0 + 2], feat[r0 + 3]);
    m7c[idx] = make_float4(K1 * b1[r0], K1 * b1[r0 + 1], K1 * b1[r0 + 2], K1 * b1[r0 + 3]);
    if (rem < 16) {   // prefix block: nodes 0..14 (+1 pad)
        int nd = rem;
        mPf[t * 16 + nd] = (nd < 15) ? feat[base + nd] : 0;
        mPc[t * 16 + nd] = (nd < 15) ? K1 * b1[base + nd] : 0.0f;
    }
}

// s = sigmoid(10*(xv+b)) = 1/(1+2^(-10*log2(e)*(xv+b))); c1 = -14.4269504*b
__device__ __forceinline__ float sigm_from(float xv, float c1) {
    float earg = fmaf(-14.426950408889634f, xv, c1);
    float e = exp2f(earg);
    return __builtin_amdgcn_rcpf(1.0f + e);
}

// ---------------- kernel 1: forest forward, STAGELESS fly + MFMA ----------
// R15: no s8, no staging phase, no fences, no in-loop barriers. Every node
// sigmoid computed on the fly from xsi (u16 read + cvt + fma/exp2/rcp) with
// per-(t,c,slot) meta tables (slot-uniform 16B loads, L2-resident). All
// instructions independent across chunks -> deep ILP; LDS = xsi only (16 KB).
// +23% sigmoid count vs staged (slot-redundant prefix), -all staging/fence
// serialization. A-frag: row=lane&15, k=(lane>>4)*8+j [m120];
// D: col=lane&15, row=(lane>>4)*4+reg [m89/m91].
__global__ __launch_bounds__(256, 2) void forest_kernel(
        const float* __restrict__ x, const _Float16* __restrict__ cwT,
        const int4* __restrict__ m46f, const float4* __restrict__ m46c,
        const int4* __restrict__ m7f, const float4* __restrict__ m7c,
        const int* __restrict__ mPf, const float* __restrict__ mPc,
        float* __restrict__ out) {
    __shared__ __align__(16) _Float16 xsi[MM * XS];     // 16384 B, read-only after fill
    // red[4][64] f4 aliased into xsi at epilogue (after full-block barrier)

    const int tid = threadIdx.x;
    const int w = tid >> 6;
    const int lane = tid & 63;
    const int b0 = blockIdx.x * RB;
    const int t0 = blockIdx.y * TPB;
    const int m = lane & 15;     // MFMA row (A) / class col (B) index
    const int slot = lane >> 4;  // MFMA k-slot == path bits b3b4

    // ---- xsi fill: coalesced global reads; one-time LDS scatter ----
    for (int idx = tid; idx < MM * RB; idx += 256) {
        int mm = idx & (MM - 1);
        int r = idx >> 9;
        xsi[mm * XS + r] = (_Float16)x[(size_t)(b0 + r) * MM + mm];
    }
    __syncthreads();   // barrier #1 (xsi is read-only from here)

    const int b3 = slot >> 1, b4 = slot & 1;
    const float sg3 = (float)(2 * b3 - 1), off3 = (float)(1 - b3);
    const float sg4 = (float)(2 * b4 - 1), off4 = (float)(1 - b4);

    f4 acc = {0.f, 0.f, 0.f, 0.f};

    // sigmoid of node with feature f, premult bias c1, at my row m
    auto sigx = [&](int f, float c1) {
        return sigm_from((float)xsi[f * XS + m], c1);
    };

    #pragma unroll
    for (int tt = 0; tt < 4; ++tt) {
        const int t = t0 + w * 4 + tt;

        // ---- B-frag loads for tree t (L2-resident; consumed per chunk) ----
        h8 bfr[8] = {};
        if (m < CC) {
            const h8* cp = reinterpret_cast<const h8*>(cwT) +
                           (((t * 8 + 0) * 8 + m) * 4 + slot);
            #pragma unroll
            for (int c = 0; c < 8; ++c) bfr[c] = cp[c * 32];  // chunk stride 32 h8
        }

        // ---- prefix meta (wave-uniform 16B loads) + 15 sigmoids ----
        const int4* pf = reinterpret_cast<const int4*>(mPf + t * 16);
        const float4* pc = reinterpret_cast<const float4*>(mPc + t * 16);
        int4 F0 = pf[0], F1 = pf[1], F2 = pf[2], F3 = pf[3];
        float4 C0 = pc[0], C1 = pc[1], C2 = pc[2], C3 = pc[3];
        float sp0 = sigx(F0.x, C0.x), sp1 = sigx(F0.y, C0.y);
        float sp2 = sigx(F0.z, C0.z), sp3 = sigx(F0.w, C0.w);
        float sp4 = sigx(F1.x, C1.x), sp5 = sigx(F1.y, C1.y);
        float sp6 = sigx(F1.z, C1.z);
        float sD3[8];
        sD3[0] = sigx(F1.w, C1.w);
        sD3[1] = sigx(F2.x, C2.x);
        sD3[2] = sigx(F2.y, C2.y);
        sD3[3] = sigx(F2.z, C2.z);
        sD3[4] = sigx(F2.w, C2.w);
        sD3[5] = sigx(F3.x, C3.x);
        sD3[6] = sigx(F3.y, C3.y);
        sD3[7] = sigx(F3.z, C3.z);

        // ---- depth-0..2 prefix products ----
        float P10 = 1.0f - sp0, P11 = sp0;
        float P200 = P10 * (1.0f - sp1), P201 = P10 * sp1;
        float P210 = P11 * (1.0f - sp2), P211 = P11 * sp2;
        float P3a[8];
        P3a[0] = P200 * (1.0f - sp3); P3a[1] = P200 * sp3;
        P3a[2] = P201 * (1.0f - sp4); P3a[3] = P201 * sp4;
        P3a[4] = P210 * (1.0f - sp5); P3a[5] = P210 * sp5;
        P3a[6] = P211 * (1.0f - sp6); P3a[7] = P211 * sp6;

        // ---- 8 chunks: fly-sigmoids for depths 4..7, DFS, MFMA ----
        const int mbase = t * 32 + slot;
        #pragma unroll
        for (int c = 0; c < 8; ++c) {
            int mi = mbase + c * 4;
            int4 f46 = m46f[mi];
            float4 c46 = m46c[mi];
            int4 f7 = m7f[mi];
            float4 c7 = m7c[mi];
            float f3 = fmaf(sg3, sD3[c], off3);
            float s4 = sigx(f46.x, c46.x);
            float f4v = fmaf(sg4, s4, off4);
            float P5 = P3a[c] * f3 * f4v;
            float s5 = sigx(f46.y, c46.y);
            float v1 = P5 * s5, v0 = P5 - v1;
            float sq0 = sigx(f46.z, c46.z);
            float sq1 = sigx(f46.w, c46.w);
            float w01 = v0 * sq0, w00 = v0 - w01;
            float w11 = v1 * sq1, w10 = v1 - w11;
            float sr0 = sigx(f7.x, c7.x);
            float sr1 = sigx(f7.y, c7.y);
            float sr2 = sigx(f7.z, c7.z);
            float sr3 = sigx(f7.w, c7.w);
            float l1 = w00 * sr0, l0 = w00 - l1;
            float l3 = w01 * sr1, l2 = w01 - l3;
            float l5 = w10 * sr2, l4 = w10 - l5;
            float l7 = w11 * sr3, l6 = w11 - l7;
            union { h8 v; h2v p[4]; } U;
            U.p[0] = pkrtz(l0, l1);
            U.p[1] = pkrtz(l2, l3);
            U.p[2] = pkrtz(l4, l5);
            U.p[3] = pkrtz(l6, l7);
            acc = __builtin_amdgcn_mfma_f32_16x16x32_f16(U.v, bfr[c], acc, 0, 0, 0);
        }
    }

    // ---- cross-wave reduction; red aliased into xsi (dead after main loop) ----
    __syncthreads();   // all waves done with xsi before alias write
    f4* red = reinterpret_cast<f4*>(xsi);
    red[w * 64 + lane] = acc;
    __syncthreads();   // barrier #2
    if (tid < 64) {
        f4 sum = red[0 * 64 + tid];
        sum += red[1 * 64 + tid];
        sum += red[2 * 64 + tid];
        sum += red[3 * 64 + tid];
        int n = tid & 15, sl = tid >> 4;
        if (n < CC) {
            #pragma unroll
            for (int reg = 0; reg < 4; ++reg) {
                int row = sl * 4 + reg;                  // D: row=(lane>>4)*4+reg
                atomicAdd(&out[(size_t)(b0 + row) * CC + n], sum[reg] * (1.0f / 64.0f));
            }
        }
    }
}

extern "C" void kernel_launch(void* const* d_in, const int* in_sizes, int n_in,
                              void* d_out, int out_size, void* d_ws, size_t ws_size,
                              hipStream_t stream) {
    const float* x  = (const float*)d_in[0];  // [B, M]
    const float* W1 = (const float*)d_in[1];  // [T, D, M] one-hot rows
    const float* b1 = (const float*)d_in[2];  // [T, D]
    // d_in[3] = Bpos, d_in[4] = Bneg: fixed complete-tree path masks (hardcoded)
    const float* Cw = (const float*)d_in[5];  // [T, K, C]
    float* out = (float*)d_out;               // [B, C] fp32

    // ws layout (rebuilt every call):
    //   cwT f16    [262144]
    //   feat int   [ 65536]
    //   m46f int4  [ 32768]   m46c float4 [ 32768]
    //   m7f  int4  [ 32768]   m7c  float4 [ 32768]
    //   mPf  int   [  4096]   mPc  float  [  4096]
    char* wsb = (char*)d_ws;
    _Float16* cwT = (_Float16*)wsb;
    int* feat   = (int*)(wsb + 262144);
    int4* m46f  = (int4*)(wsb + 327680);
    float4* m46c = (float4*)(wsb + 360448);
    int4* m7f   = (int4*)(wsb + 393216);
    float4* m7c = (float4*)(wsb + 425984);
    int* mPf    = (int*)(wsb + 458752);
    float* mPc  = (float*)(wsb + 462848);

    (void)hipMemsetAsync(out, 0, (size_t)BB * CC * sizeof(float), stream);
    feat_kernel<<<(TT * DD) / 4, 256, 0, stream>>>(W1, feat);
    cwt_kernel<<<(TT * KK) / 256, 256, 0, stream>>>(Cw, cwT);
    meta_kernel<<<(TT * 32 + 255) / 256, 256, 0, stream>>>(feat, b1, m46f, m46c,
                                                           m7f, m7c, mPf, mPc);
    forest_kernel<<<dim3(BB / RB, TT / TPB), 256, 0, stream>>>(
        x, cwT, m46f, m46c, m7f, m7c, mPf, mPc, out);
}

// Round 16
// 141.115 us; speedup vs baseline: 1.0506x; 1.0506x over previous
//
#include <hip/hip_runtime.h>
#include <hip/hip_bf16.h>

#define TT 64
#define DD 255
#define KK 256
#define MM 512
#define CC 8
#define BB 4096
#define RB 16    // rows per block = MFMA M
#define TPB 16   // trees per block (4 per wave)
#define ST 18    // s8 node stride in halfs (9 dwords, odd -> bank-spread)
#define XS 16    // xsi feature stride in halfs (32B, 16B-aligned -> b128 gather)

typedef _Float16 h8 __attribute__((ext_vector_type(8)));
typedef _Float16 h2v __attribute__((ext_vector_type(2)));
typedef float f4 __attribute__((ext_vector_type(4)));
typedef uint32_t u32a __attribute__((may_alias));

// cvt_pkrtz returns __fp16x2; bit-cast to our _Float16x2
__device__ __forceinline__ h2v pkrtz(float a, float b) {
    return __builtin_bit_cast(h2v, __builtin_amdgcn_cvt_pkrtz(a, b));
}

__device__ __forceinline__ float wave_sum(float v) {
    v += __shfl_down(v, 32, 64);
    v += __shfl_down(v, 16, 64);
    v += __shfl_down(v, 8, 64);
    v += __shfl_down(v, 4, 64);
    v += __shfl_down(v, 2, 64);
    v += __shfl_down(v, 1, 64);
    return v;
}

// ---------------- kernel 0: extract feature index from one-hot W1 ----------
__global__ void feat_kernel(const float* __restrict__ W1, int* __restrict__ feat) {
    const int row = blockIdx.x * 4 + (threadIdx.x >> 6);
    const int lane = threadIdx.x & 63;
    const float4* r = reinterpret_cast<const float4*>(W1 + (size_t)row * MM);
    float4 a = r[lane];
    float4 b = r[lane + 64];
    float ba = (float)(4 * lane);
    float bb = (float)(4 * (lane + 64));
    float acc = 0.0f;
    acc = fmaf(a.x, ba,        acc);
    acc = fmaf(a.y, ba + 1.0f, acc);
    acc = fmaf(a.z, ba + 2.0f, acc);
    acc = fmaf(a.w, ba + 3.0f, acc);
    acc = fmaf(b.x, bb,        acc);
    acc = fmaf(b.y, bb + 1.0f, acc);
    acc = fmaf(b.z, bb + 2.0f, acc);
    acc = fmaf(b.w, bb + 3.0f, acc);
    acc = wave_sum(acc);
    if (lane == 0) feat[row] = (int)(acc + 0.5f);
}

// ---------------- kernel 0b: merged prep (cwT transpose + depth-7 meta) ----
// blocks [0, 64): cwT — cwT[(((t*8+c)*8+cls)*4+slot)*8+j] = Cw[t][k][cls]
// blocks [64, 72): m7f/m7c — depth-7 quad per (t, chunk, slotgrp)
__global__ void prep_kernel(const float* __restrict__ Cw, _Float16* __restrict__ cwT,
                            const int* __restrict__ feat, const float* __restrict__ b1,
                            int4* __restrict__ m7f, float4* __restrict__ m7c) {
    if (blockIdx.x < 64) {
        int idx = blockIdx.x * 256 + threadIdx.x;   // t*256 + k
        int t = idx >> 8, k = idx & 255;
        int c = k >> 5, sl = (k >> 3) & 3, j = k & 7;
        const float4* p = reinterpret_cast<const float4*>(Cw + (size_t)idx * CC);
        float4 p0 = p[0], p1 = p[1];
        _Float16* base = cwT + ((((t * 8 + c) * 8) * 4 + sl) * 8 + j);  // cls stride 32
        base[0 * 32] = (_Float16)p0.x;
        base[1 * 32] = (_Float16)p0.y;
        base[2 * 32] = (_Float16)p0.z;
        base[3 * 32] = (_Float16)p0.w;
        base[4 * 32] = (_Float16)p1.x;
        base[5 * 32] = (_Float16)p1.y;
        base[6 * 32] = (_Float16)p1.z;
        base[7 * 32] = (_Float16)p1.w;
    } else {
        int idx = (blockIdx.x - 64) * 256 + threadIdx.x;   // t*32 + c*4 + sg
        if (idx >= TT * 32) return;
        int t = idx >> 5, rem = idx & 31;
        int c = rem >> 2, sg = rem & 3;
        int r0 = t * DD + 127 + 16 * c + 4 * sg;
        m7f[idx] = make_int4(feat[r0], feat[r0 + 1], feat[r0 + 2], feat[r0 + 3]);
        const float K1 = -14.426950408889634f;
        m7c[idx] = make_float4(K1 * b1[r0], K1 * b1[r0 + 1],
                               K1 * b1[r0 + 2], K1 * b1[r0 + 3]);
    }
}

// s = sigmoid(10*(xv+b)) = 1/(1+2^(-10*log2(e)*(xv+b))); c1 = -14.4269504*b
__device__ __forceinline__ float sigm_from(float xv, float c1) {
    float earg = fmaf(-14.426950408889634f, xv, c1);
    float e = exp2f(earg);
    return __builtin_amdgcn_rcpf(1.0f + e);
}

// ---------------- kernel 1: forest forward, pipelined dbuf + MFMA ---------
// R14 best-known config (42.9 µs): per-wave double-buffered s8, software
// pipeline stage(t+1) || path(t), depth-7 folded on-the-fly from m7 meta.
// No explicit lgkm drain: TBAA no-alias lets the compiler interleave the
// phases (disjoint buffers — safe); per-iteration asm barrier pins
// cross-iteration WAR/RAW (buffer reuse 2 trees apart; DS in-order per wave).
// LDS 53,248 B -> 3 blocks/CU. Theory ledger: occupancy x (R13), pipelining
// marginal (R14), stageless x (R15 +10%) — this is the structure's floor.
// A-frag: row=lane&15, k=(lane>>4)*8+j [m120]; D: col=lane&15, row=quad*4+reg.
__global__ __launch_bounds__(256, 2) void forest_kernel(
        const float* __restrict__ x, const float* __restrict__ b1,
        const _Float16* __restrict__ cwT, const int* __restrict__ feat,
        const int4* __restrict__ m7f, const float4* __restrict__ m7c,
        float* __restrict__ out) {
    __shared__ __align__(16) _Float16 xsi[MM * XS];     // 16384 B
    __shared__ _Float16 s8[4][2][128 * ST];             // 36864 B (nodes 0..126 x2)
    // red[4][64] f4 aliased into xsi at epilogue (after full-block barrier)

    const int tid = threadIdx.x;
    const int w = tid >> 6;
    const int lane = tid & 63;
    const int b0 = blockIdx.x * RB;
    const int t0 = blockIdx.y * TPB;
    const int m = lane & 15;     // MFMA row (A) / class col (B) index
    const int slot = lane >> 4;  // MFMA k-slot == depth-7 slot group

    // ---- xsi fill: coalesced global reads; one-time LDS scatter ----
    for (int idx = tid; idx < MM * RB; idx += 256) {
        int mm = idx & (MM - 1);
        int r = idx >> 9;
        xsi[mm * XS + r] = (_Float16)x[(size_t)(b0 + r) * MM + mm];
    }
    __syncthreads();   // barrier #1

    const int b3 = slot >> 1, b4 = slot & 1;
    const float sg3 = (float)(2 * b3 - 1), off3 = (float)(1 - b3);
    const float sg4 = (float)(2 * b4 - 1), off4 = (float)(1 - b4);

    f4 acc = {0.f, 0.f, 0.f, 0.f};

    auto ldmeta = [&](int t, int kq, int& f, float& c1) {
        int d = kq * 64 + lane;
        int idx = t * DD + (d < 127 ? d : 0);
        f = feat[idx];
        c1 = -14.426950408889634f * b1[idx];
    };

    // stage tree's sigmoids (nodes 0..126) into the given buffer
    auto stage = [&](_Float16* buf, const int* fm, const float* cm) {
        #pragma unroll
        for (int kq = 0; kq < 2; ++kq) {
            int d = kq * 64 + lane;
            if (d < 127) {
                const float4* xp = reinterpret_cast<const float4*>(xsi + fm[kq] * XS);
                float4 A = xp[0], Bv = xp[1];
                float c1 = cm[kq];
                u32a* sp = reinterpret_cast<u32a*>(buf + d * ST);
                uint32_t raw[8] = {
                    __builtin_bit_cast(uint32_t, A.x), __builtin_bit_cast(uint32_t, A.y),
                    __builtin_bit_cast(uint32_t, A.z), __builtin_bit_cast(uint32_t, A.w),
                    __builtin_bit_cast(uint32_t, Bv.x), __builtin_bit_cast(uint32_t, Bv.y),
                    __builtin_bit_cast(uint32_t, Bv.z), __builtin_bit_cast(uint32_t, Bv.w)};
                #pragma unroll
                for (int i2 = 0; i2 < 8; ++i2) {
                    h2v u = __builtin_bit_cast(h2v, raw[i2]);
                    float sa = sigm_from((float)u.x, c1);
                    float sb = sigm_from((float)u.y, c1);
                    sp[i2] = __builtin_bit_cast(uint32_t, pkrtz(sa, sb));
                }
            }
        }
    };

    // ---- pipeline prologue: meta(t0) -> stage buf0; meta(t0+1) ----
    int fA[2], fB[2]; float cA[2], cB[2];
    #pragma unroll
    for (int kq = 0; kq < 2; ++kq) ldmeta(t0 + w * 4, kq, fA[kq], cA[kq]);
    stage(s8[w][0], fA, cA);
    #pragma unroll
    for (int kq = 0; kq < 2; ++kq) ldmeta(t0 + w * 4 + 1, kq, fA[kq], cA[kq]);

    #pragma unroll
    for (int tt = 0; tt < 4; ++tt) {
        const int t = t0 + w * 4 + tt;

        // cross-iteration fence: prevents hoisting this iteration's staging
        // writes above last iteration's path reads (TBAA can't see the alias).
        asm volatile("" ::: "memory");

        // ---- B-frag loads for tree t (vmcnt; consumed at iteration end) ----
        h8 bfr[8] = {};
        if (m < CC) {
            const h8* cp = reinterpret_cast<const h8*>(cwT) +
                           (((t * 8 + 0) * 8 + m) * 4 + slot);
            #pragma unroll
            for (int c = 0; c < 8; ++c) bfr[c] = cp[c * 32];  // chunk stride 32 h8
        }

        // ---- stage tree t+1 into the other buffer; prefetch meta(t+2) ----
        if (tt < 3) {
            stage(s8[w][(tt + 1) & 1], fA, cA);
            if (tt < 2) {
                #pragma unroll
                for (int kq = 0; kq < 2; ++kq) ldmeta(t + 2, kq, fB[kq], cB[kq]);
            }
        }

        _Float16* s8w = s8[w][tt & 1];

        // ---- depth-0..2 prefix products (8 of them, one per chunk) ----
        float s0 = (float)s8w[0 * ST + m];
        float s1 = (float)s8w[1 * ST + m];
        float s2 = (float)s8w[2 * ST + m];
        float s3 = (float)s8w[3 * ST + m];
        float s4 = (float)s8w[4 * ST + m];
        float s5p = (float)s8w[5 * ST + m];
        float s6 = (float)s8w[6 * ST + m];
        float P10 = 1.0f - s0, P11 = s0;
        float P200 = P10 * (1.0f - s1), P201 = P10 * s1;
        float P210 = P11 * (1.0f - s2), P211 = P11 * s2;
        float P3a[8];
        P3a[0] = P200 * (1.0f - s3); P3a[1] = P200 * s3;
        P3a[2] = P201 * (1.0f - s4); P3a[3] = P201 * s4;
        P3a[4] = P210 * (1.0f - s5p); P3a[5] = P210 * s5p;
        P3a[6] = P211 * (1.0f - s6); P3a[7] = P211 * s6;

        // ---- 8 chunks: DFS levels 3..6 from s8, level 7 on the fly, MFMA ----
        #pragma unroll
        for (int c = 0; c < 8; ++c) {
            const int n3 = 7 + c;                       // depth-3 node (compile-time)
            float sc3 = (float)s8w[n3 * ST + m];
            float f3 = fmaf(sg3, sc3, off3);
            int n4 = 2 * n3 + 1 + b3;
            float sc4 = (float)s8w[n4 * ST + m];
            float f4v = fmaf(sg4, sc4, off4);
            float P5 = P3a[c] * f3 * f4v;
            int n5 = 2 * n4 + 1 + b4;                   // octet root (depth 5)
            float s5 = (float)s8w[n5 * ST + m];
            float v1 = P5 * s5, v0 = P5 - v1;
            int q0 = 2 * n5 + 1;                        // depth-6 pair (<=126)
            float sq0 = (float)s8w[q0 * ST + m];
            float sq1 = (float)s8w[(q0 + 1) * ST + m];
            float w01 = v0 * sq0, w00 = v0 - w01;
            float w11 = v1 * sq1, w10 = v1 - w11;
            // depth-7 on the fly: 4 sigmoids from xsi + premultiplied meta
            int midx = (t * 8 + c) * 4 + slot;
            int4 fr = m7f[midx];
            float4 cr = m7c[midx];
            float sr0 = sigm_from((float)xsi[fr.x * XS + m], cr.x);
            float sr1 = sigm_from((float)xsi[fr.y * XS + m], cr.y);
            float sr2 = sigm_from((float)xsi[fr.z * XS + m], cr.z);
            float sr3 = sigm_from((float)xsi[fr.w * XS + m], cr.w);
            float l1 = w00 * sr0, l0 = w00 - l1;
            float l3 = w01 * sr1, l2 = w01 - l3;
            float l5 = w10 * sr2, l4 = w10 - l5;
            float l7 = w11 * sr3, l6 = w11 - l7;
            union { h8 v; h2v p[4]; } U;
            U.p[0] = pkrtz(l0, l1);
            U.p[1] = pkrtz(l2, l3);
            U.p[2] = pkrtz(l4, l5);
            U.p[3] = pkrtz(l6, l7);
            acc = __builtin_amdgcn_mfma_f32_16x16x32_f16(U.v, bfr[c], acc, 0, 0, 0);
        }

        // rotate meta pipeline: A <- B
        #pragma unroll
        for (int kq = 0; kq < 2; ++kq) { fA[kq] = fB[kq]; cA[kq] = cB[kq]; }
    }

    // ---- cross-wave reduction; red aliased into xsi (dead after main loop) ----
    __syncthreads();   // all waves done with xsi/s8 before alias write
    f4* red = reinterpret_cast<f4*>(xsi);
    red[w * 64 + lane] = acc;
    __syncthreads();   // barrier #2
    if (tid < 64) {
        f4 sum = red[0 * 64 + tid];
        sum += red[1 * 64 + tid];
        sum += red[2 * 64 + tid];
        sum += red[3 * 64 + tid];
        int n = tid & 15, sl = tid >> 4;
        if (n < CC) {
            #pragma unroll
            for (int reg = 0; reg < 4; ++reg) {
                int row = sl * 4 + reg;                  // D: row=(lane>>4)*4+reg
                atomicAdd(&out[(size_t)(b0 + row) * CC + n], sum[reg] * (1.0f / 64.0f));
            }
        }
    }
}

extern "C" void kernel_launch(void* const* d_in, const int* in_sizes, int n_in,
                              void* d_out, int out_size, void* d_ws, size_t ws_size,
                              hipStream_t stream) {
    const float* x  = (const float*)d_in[0];  // [B, M]
    const float* W1 = (const float*)d_in[1];  // [T, D, M] one-hot rows
    const float* b1 = (const float*)d_in[2];  // [T, D]
    // d_in[3] = Bpos, d_in[4] = Bneg: fixed complete-tree path masks (hardcoded)
    const float* Cw = (const float*)d_in[5];  // [T, K, C]
    float* out = (float*)d_out;               // [B, C] fp32

    // ws layout (rebuilt every call):
    //   cwT f16   [262144 B]
    //   feat int  [ 65536 B pad]
    //   m7f int4  [ 32768 B]
    //   m7c float4[ 32768 B]
    char* wsb = (char*)d_ws;
    _Float16* cwT = (_Float16*)wsb;
    int* feat = (int*)(wsb + 262144);
    int4* m7f = (int4*)(wsb + 262144 + 65536);
    float4* m7c = (float4*)(wsb + 262144 + 65536 + 32768);

    (void)hipMemsetAsync(out, 0, (size_t)BB * CC * sizeof(float), stream);
    feat_kernel<<<(TT * DD) / 4, 256, 0, stream>>>(W1, feat);
    prep_kernel<<<64 + 8, 256, 0, stream>>>(Cw, cwT, feat, b1, m7f, m7c);
    forest_kernel<<<dim3(BB / RB, TT / TPB), 256, 0, stream>>>(x, b1, cwT, feat, m7f, m7c, out);
}